// Round 1
// baseline (645953.906 us; speedup 1.0000x reference)
//
#include <hip/hip_runtime.h>

#define NINP 34
#define NCC  128
#define NHH  512
#define BBB  64
#define SSS  2048
#define TTT  400
#define GEPS 1e-10f

#define GDIM 544
#define NTHR 256
#define NCHK 8        // attention S-chunks
#define SCHK 256      // S per chunk

// If output 2 (generated) fails while outputs 0/1 pass, flip to 0 (legacy jax threefry).
#define JAX_PARTITIONABLE 1

// ws float offsets (after 8192-byte sync header)
#define OFF_H   0          // h double buffer: 2*3*B*NH = 196608
#define OFF_C   196608     // c: 3*B*NH = 98304
#define OFF_CTX 294912     // B*NC = 8192
#define OFF_Q   303104     // B*NC = 8192
#define OFF_E   311296     // B*S = 131072
#define OFF_P   442368     // B*NCHK*130 = 66560
// total floats = 508928 (~2.0 MB) + 8 KB sync header

struct Params {
  const float* keys; const float* values;
  const int* lens;  const int* toks;
  const float* emb; const float* wq; const float* bq;
  const float* wc;  const float* bc; const float* bout;
  const float* wih[3]; const float* whh[3];
  const float* bih[3]; const float* bhh[3];
  const float* h0[3];  const float* c0[3];
  float* out_logits; float* out_att; float* out_gen;
  float* wsf; unsigned* sync;
};

__device__ __forceinline__ float4 ld4(const float* p) { return *(const float4*)p; }
__device__ __forceinline__ float sigf(float x) { return 1.0f / (1.0f + expf(-x)); }

__device__ __forceinline__ unsigned aload(const unsigned* p) {
  return __hip_atomic_load(p, __ATOMIC_ACQUIRE, __HIP_MEMORY_SCOPE_AGENT);
}
__device__ __forceinline__ unsigned aadd(unsigned* p, unsigned v) {
  return __hip_atomic_fetch_add(p, v, __ATOMIC_ACQ_REL, __HIP_MEMORY_SCOPE_AGENT);
}
__device__ __forceinline__ void astore(unsigned* p, unsigned v) {
  __hip_atomic_store(p, v, __ATOMIC_RELAXED, __HIP_MEMORY_SCOPE_AGENT);
}

// Hierarchical grid barrier: 32 leaves x 17 blocks. sync[0]=root, sync[1]=gen,
// leaves at sync[128 + 32*leaf] (one 128B line each).
__device__ void gbar(unsigned* sync, unsigned& epoch) {
  __threadfence();
  __syncthreads();
  if (threadIdx.x == 0) {
    epoch++;
    const int leaf = blockIdx.x / 17;
    unsigned a1 = aadd(&sync[128 + 32 * leaf], 1u);
    if (a1 == 16u) {                 // last in leaf
      astore(&sync[128 + 32 * leaf], 0u);
      unsigned a2 = aadd(&sync[0], 1u);
      if (a2 == 31u) {               // last leaf
        astore(&sync[0], 0u);
        aadd(&sync[1], 1u);          // bump generation (release)
      }
    }
    while (aload(&sync[1]) < epoch) __builtin_amdgcn_s_sleep(2);
  }
  __syncthreads();
  __threadfence();
}

__device__ __forceinline__ void waitflag(unsigned* p, unsigned target) {
  if (threadIdx.x == 0) {
    while (aload(p) < target) __builtin_amdgcn_s_sleep(2);
  }
  __syncthreads();
  __threadfence();
}
__device__ __forceinline__ void postflag(unsigned* p) {
  __threadfence();
  __syncthreads();
  if (threadIdx.x == 0) aadd(p, 1u);
}

// ---------------- Threefry2x32-20, jax.random.key(1) => (k0,k1)=(0,1) ----------------
__device__ __forceinline__ void tfr(unsigned& x0, unsigned& x1, int r) {
  x0 += x1; x1 = (x1 << r) | (x1 >> (32 - r)); x1 ^= x0;
}
__device__ unsigned threefry_bits(unsigned idx) {
  const unsigned k0 = 0u, k1 = 1u;
  const unsigned k2 = 0x1BD11BDAu ^ k0 ^ k1;
#if JAX_PARTITIONABLE
  unsigned x0 = 0u, x1 = idx;
#else
  const unsigned half = (TTT * BBB * NINP) / 2;  // 435200 (even total)
  const bool lo = idx < half;
  unsigned x0 = lo ? idx : idx - half;
  unsigned x1 = lo ? idx + half : idx;
#endif
  x0 += k0; x1 += k1;
  tfr(x0,x1,13); tfr(x0,x1,15); tfr(x0,x1,26); tfr(x0,x1,6);
  x0 += k1; x1 += k2 + 1u;
  tfr(x0,x1,17); tfr(x0,x1,29); tfr(x0,x1,16); tfr(x0,x1,24);
  x0 += k2; x1 += k0 + 2u;
  tfr(x0,x1,13); tfr(x0,x1,15); tfr(x0,x1,26); tfr(x0,x1,6);
  x0 += k0; x1 += k1 + 3u;
  tfr(x0,x1,17); tfr(x0,x1,29); tfr(x0,x1,16); tfr(x0,x1,24);
  x0 += k1; x1 += k2 + 4u;
  tfr(x0,x1,13); tfr(x0,x1,15); tfr(x0,x1,26); tfr(x0,x1,6);
  x0 += k2; x1 += k0 + 5u;
#if JAX_PARTITIONABLE
  return x0 ^ x1;
#else
  return lo ? x0 : x1;
#endif
}
__device__ __forceinline__ float gumbel(unsigned idx) {
  unsigned bits = threefry_bits(idx);
  float u = __uint_as_float((bits >> 9) | 0x3f800000u) - 1.0f;
  u = fmaxf(u, 0.0f);
  return -logf(GEPS - logf(u + GEPS));
}

// ---------------- LSTM layer phase: blocks [0,NH), block = one hidden index j ----------------
// thread: b = tid&63 (lane), g = tid>>6 (wave = gate i/f/g/o)
template<int L>
__device__ void lstm_layer(const Params& p, int t, const float* hin, float* hout,
                           float* sh, int bid, int tid) {
  const float* hin_l = hin + L * BBB * NHH;
  float* houtl = hout + L * BBB * NHH;
  float* cl = p.wsf + OFF_C + L * BBB * NHH;
  const float* xlow = (L == 0) ? (const float*)0 : (hout + (L - 1) * BBB * NHH);

  const int b = tid & 63;
  const int g = tid >> 6;
  const int j = bid;
  const int row = g * NHH + j;
  const int insz = (L == 0) ? (2 * NCC) : NHH;
  const int nx = insz >> 7;  // chunks of 128 in the x-part (2 or 4)

  const float* wr  = p.wih[L] + (size_t)row * insz;
  const float* wr2 = p.whh[L] + (size_t)row * NHH;
  float acc = p.bih[L][row] + p.bhh[L][row];
  float s0 = 0.f, s1 = 0.f, s2 = 0.f, s3 = 0.f;

  for (int cc = 0; cc < nx + 4; ++cc) {
    const bool isx = cc < nx;
    const int off = (isx ? cc : cc - nx) << 7;
    __syncthreads();
    // stage 64x128 source tile into sh (row stride 132 to kill bank conflicts)
    for (int i = tid; i < 2048; i += NTHR) {   // 2048 float4s
      const int rb = i >> 5;
      const int kk = (i & 31) << 2;
      float4 v;
      if (L == 0) {
        if (isx) {
          if (cc == 0) v = ld4(p.emb + (size_t)p.toks[rb * TTT + t] * NCC + kk);
          else         v = ld4(p.wsf + OFF_CTX + rb * NCC + kk);
        } else {
          v = ld4(hin_l + (size_t)rb * NHH + off + kk);
        }
      } else {
        if (isx) v = ld4(xlow + (size_t)rb * NHH + off + kk);
        else     v = ld4(hin_l + (size_t)rb * NHH + off + kk);
      }
      *(float4*)&sh[rb * 132 + kk] = v;
    }
    __syncthreads();
    const float* wp = (isx ? wr : wr2) + off;
    const float* xr = sh + b * 132;
#pragma unroll 8
    for (int k = 0; k < 128; k += 4) {
      float4 w = ld4(wp + k);
      float4 x = ld4(xr + k);
      s0 = fmaf(w.x, x.x, s0); s1 = fmaf(w.y, x.y, s1);
      s2 = fmaf(w.z, x.z, s2); s3 = fmaf(w.w, x.w, s3);
    }
  }
  acc += (s0 + s1) + (s2 + s3);

  // combine the 4 gates (one per wave) via LDS tail region
  float* gl = sh + 8448;  // 256 floats
  gl[g * 64 + b] = acc;
  __syncthreads();
  if (tid < 64) {
    const int bb = tid;
    const float iv = gl[bb], fv = gl[64 + bb], gv = gl[128 + bb], ov = gl[192 + bb];
    const float cold = cl[bb * NHH + j];
    const float cnew = sigf(fv) * cold + sigf(iv) * tanhf(gv);
    const float hnew = sigf(ov) * tanhf(cnew);
    cl[bb * NHH + j] = cnew;
    houtl[bb * NHH + j] = hnew;
  }
}

// ---------------- fused attention phase ----------------
// blocks [0,512): E-blocks (b = bid>>3, chunk = bid&7)
// blocks [512,544): C-blocks: q c-tile, then per-b combine/att/ctx/z/logits/gen
__device__ void attend_phase(const Params& p, int a, int t, const float* h3,
                             float* sh, int bid, int tid, bool wout) {
  float* wsf = p.wsf;
  unsigned* sync = p.sync;

  if (bid >= NHH) {
    const int cb = bid - NHH;  // 0..31
    // ---- q tile: c = cb*4 + wave, all 64 b per wave ----
    {
      const int b = tid & 63;
      const int ci = tid >> 6;
      const int c = cb * 4 + ci;
      const float* wr = p.wq + (size_t)c * NHH;
      float s0 = 0.f, s1 = 0.f, s2 = 0.f, s3 = 0.f;
      for (int cc = 0; cc < 4; ++cc) {
        __syncthreads();
        for (int i = tid; i < 2048; i += NTHR) {
          const int rb = i >> 5;
          const int kk = (i & 31) << 2;
          *(float4*)&sh[rb * 132 + kk] = ld4(h3 + (size_t)rb * NHH + cc * 128 + kk);
        }
        __syncthreads();
        const float* wp = wr + cc * 128;
        const float* xr = sh + b * 132;
#pragma unroll 8
        for (int k = 0; k < 128; k += 4) {
          float4 w = ld4(wp + k);
          float4 x = ld4(xr + k);
          s0 = fmaf(w.x, x.x, s0); s1 = fmaf(w.y, x.y, s1);
          s2 = fmaf(w.z, x.z, s2); s3 = fmaf(w.w, x.w, s3);
        }
      }
      wsf[OFF_Q + b * NCC + c] = p.bq[c] + (s0 + s1) + (s2 + s3);
    }
    postflag(&sync[2]);  // qdone++

    // ---- per-b tail ----
    for (int bi = 0; bi < 2; ++bi) {
      const int b = cb * 2 + bi;
      waitflag(&sync[16 + b], (unsigned)(NCHK * (a + 1)));
      const float* pb = wsf + OFF_P + ((size_t)b * NCHK) * 130;
      float m = -1e30f;
#pragma unroll
      for (int ch = 0; ch < NCHK; ++ch) m = fmaxf(m, pb[ch * 130]);
      float Lsum = 0.f;
#pragma unroll
      for (int ch = 0; ch < NCHK; ++ch) Lsum += pb[ch * 130 + 1] * expf(pb[ch * 130] - m);

      float* us = sh;  // 640: [h3 row | ctx]
      if (tid < NCC) {
        float v = 0.f;
#pragma unroll
        for (int ch = 0; ch < NCHK; ++ch) v += pb[ch * 130 + 2 + tid] * expf(pb[ch * 130] - m);
        v /= Lsum;
        wsf[OFF_CTX + b * NCC + tid] = v;
        us[NHH + tid] = v;
      }
      for (int k = tid; k < NHH; k += NTHR) us[k] = h3[(size_t)b * NHH + k];
      __syncthreads();

      if (wout) {
        // attention row out
        const float* eb = wsf + OFF_E + (size_t)b * SSS;
        float* ao = p.out_att + ((size_t)t * BBB + b) * SSS;
        for (int s = tid; s < SSS; s += NTHR) ao[s] = expf(eb[s] - m) / Lsum;
        // z = leaky_relu([h3|ctx] @ wc^T + bc)
        float* zs = sh + 704;
        if (tid < NCC) {
          const float* wr = p.wc + (size_t)tid * (NHH + NCC);
          float s0 = 0.f, s1 = 0.f, s2 = 0.f, s3 = 0.f;
#pragma unroll 8
          for (int k = 0; k < NHH + NCC; k += 4) {
            float4 w = ld4(wr + k);
            s0 = fmaf(w.x, us[k],     s0); s1 = fmaf(w.y, us[k + 1], s1);
            s2 = fmaf(w.z, us[k + 2], s2); s3 = fmaf(w.w, us[k + 3], s3);
          }
          float z = (s0 + s1) + (s2 + s3) + p.bc[tid];
          zs[tid] = (z >= 0.f) ? z : 0.01f * z;
        }
        __syncthreads();
        // logits (tied emb weights) + gumbel argmax
        float* lg = sh + 840;
        if (tid < NINP) {
          const float* er = p.emb + tid * NCC;
          float s0 = 0.f, s1 = 0.f, s2 = 0.f, s3 = 0.f;
#pragma unroll 8
          for (int k = 0; k < NCC; k += 4) {
            float4 w = ld4(er + k);
            s0 = fmaf(w.x, zs[k],     s0); s1 = fmaf(w.y, zs[k + 1], s1);
            s2 = fmaf(w.z, zs[k + 2], s2); s3 = fmaf(w.w, zs[k + 3], s3);
          }
          const float lgt = (s0 + s1) + (s2 + s3) + p.bout[tid];
          p.out_logits[((size_t)t * BBB + b) * NINP + tid] = lgt;
          lg[tid] = lgt + gumbel((unsigned)(t * (BBB * NINP) + b * NINP + tid));
        }
        __syncthreads();
        if (tid == 0) {
          float bv = lg[0]; int bix = 0;
          for (int i = 1; i < NINP; ++i) if (lg[i] > bv) { bv = lg[i]; bix = i; }
          p.out_gen[t * BBB + b] = (float)bix;
        }
        __syncthreads();
      } else {
        __syncthreads();
      }
    }
  } else {
    // ---- E-block: one (b, s-chunk) ----
    const int b = bid >> 3;
    const int ch = bid & 7;
    const int sbase = ch * SCHK;
    waitflag(&sync[2], (unsigned)(32 * (a + 1)));

    float* qs = sh;         // 128
    float* ps = sh + 128;   // 256
    float* red = sh + 384;  // 8*132
    if (tid < NCC) qs[tid] = wsf[OFF_Q + b * NCC + tid];
    const int lenb = p.lens[b];
    __syncthreads();

    const int s = sbase + tid;
    const float* kr = p.keys + ((size_t)b * SSS + s) * NCC;
    float e0 = 0.f, e1 = 0.f, e2 = 0.f, e3 = 0.f;
#pragma unroll 8
    for (int c = 0; c < NCC; c += 4) {
      float4 kv = ld4(kr + c);
      e0 = fmaf(qs[c],     kv.x, e0); e1 = fmaf(qs[c + 1], kv.y, e1);
      e2 = fmaf(qs[c + 2], kv.z, e2); e3 = fmaf(qs[c + 3], kv.w, e3);
    }
    float e = (e0 + e1) + (e2 + e3);
    const bool msk = s < lenb;
    e = msk ? e : -1e6f;
    wsf[OFF_E + (size_t)b * SSS + s] = e;

    // chunk max
    float mx = e;
#pragma unroll
    for (int off = 32; off; off >>= 1) mx = fmaxf(mx, __shfl_xor(mx, off));
    if ((tid & 63) == 0) red[tid >> 6] = mx;
    __syncthreads();
    const float mc = fmaxf(fmaxf(red[0], red[1]), fmaxf(red[2], red[3]));
    const float pv = msk ? expf(e - mc) : 0.f;
    ps[tid] = pv;
    float ls = pv;
#pragma unroll
    for (int off = 32; off; off >>= 1) ls += __shfl_xor(ls, off);
    if ((tid & 63) == 0) red[4 + (tid >> 6)] = ls;
    __syncthreads();
    const float lc = (red[4] + red[5]) + (red[6] + red[7]);

    // ctx partial: thread = (s-group of 32, c-float4)
    const int c4 = (tid & 31) << 2;
    const int sg = tid >> 5;
    float r0 = 0.f, r1 = 0.f, r2 = 0.f, r3 = 0.f;
    const float* vb = p.values + ((size_t)b * SSS + sbase + sg * 32) * NCC + c4;
#pragma unroll 4
    for (int i2 = 0; i2 < 32; ++i2) {
      const float pw = ps[sg * 32 + i2];
      float4 vv = ld4(vb + (size_t)i2 * NCC);
      r0 = fmaf(pw, vv.x, r0); r1 = fmaf(pw, vv.y, r1);
      r2 = fmaf(pw, vv.z, r2); r3 = fmaf(pw, vv.w, r3);
    }
    __syncthreads();
    *(float4*)&red[sg * 132 + c4] = make_float4(r0, r1, r2, r3);
    __syncthreads();
    float* pout = wsf + OFF_P + ((size_t)b * NCHK + ch) * 130;
    if (tid < NCC) {
      float sum = 0.f;
#pragma unroll
      for (int sg2 = 0; sg2 < 8; ++sg2) sum += red[sg2 * 132 + tid];
      pout[2 + tid] = sum;
    }
    if (tid == 0) { pout[0] = mc; pout[1] = lc; }
    postflag(&sync[16 + b]);
  }
}

extern "C" __global__ void __launch_bounds__(NTHR, 4)
decoder_kernel(Params p) {
  __shared__ float sh[8704];  // 34,816 B
  const int bid = blockIdx.x;
  const int tid = threadIdx.x;
  unsigned epoch = 0;
  unsigned* sync = p.sync;
  float* wsf = p.wsf;

  // init h (buffer 0) and c from h0/c0 params
  for (int i = bid * NTHR + tid; i < 3 * BBB * NHH; i += GDIM * NTHR) {
    const int l = i / (BBB * NHH);
    const int j = i & (NHH - 1);
    wsf[OFF_H + i] = p.h0[l][j];
    wsf[OFF_C + i] = p.c0[l][j];
  }
  gbar(sync, epoch);

  // initial attend from h0_2 (ctx only, no outputs)
  attend_phase(p, 0, -1, wsf + OFF_H + 2 * BBB * NHH, sh, bid, tid, false);
  gbar(sync, epoch);

  for (int t = 0; t < TTT; ++t) {
    const float* hin = wsf + OFF_H + ((t & 1) ? 3 * BBB * NHH : 0);
    float* hout      = wsf + OFF_H + ((t & 1) ? 0 : 3 * BBB * NHH);

    if (bid < NHH) lstm_layer<0>(p, t, hin, hout, sh, bid, tid);
    gbar(sync, epoch);
    if (bid < NHH) lstm_layer<1>(p, t, hin, hout, sh, bid, tid);
    gbar(sync, epoch);
    if (bid < NHH) lstm_layer<2>(p, t, hin, hout, sh, bid, tid);
    gbar(sync, epoch);
    attend_phase(p, t + 1, t, hout + 2 * BBB * NHH, sh, bid, tid, true);
    gbar(sync, epoch);
  }
}

extern "C" void kernel_launch(void* const* d_in, const int* in_sizes, int n_in,
                              void* d_out, int out_size, void* d_ws, size_t ws_size,
                              hipStream_t stream) {
  Params p;
  p.keys   = (const float*)d_in[0];
  p.values = (const float*)d_in[1];
  p.lens   = (const int*)d_in[2];
  p.toks   = (const int*)d_in[3];
  p.emb    = (const float*)d_in[4];
  p.wq     = (const float*)d_in[5];
  p.bq     = (const float*)d_in[6];
  p.wc     = (const float*)d_in[7];
  p.bc     = (const float*)d_in[8];
  p.bout   = (const float*)d_in[9];
  for (int l = 0; l < 3; ++l) {
    p.wih[l] = (const float*)d_in[10 + 6 * l];
    p.whh[l] = (const float*)d_in[11 + 6 * l];
    p.bih[l] = (const float*)d_in[12 + 6 * l];
    p.bhh[l] = (const float*)d_in[13 + 6 * l];
    p.h0[l]  = (const float*)d_in[14 + 6 * l];
    p.c0[l]  = (const float*)d_in[15 + 6 * l];
  }
  float* out = (float*)d_out;
  p.out_logits = out;                                          // [T,B,NINP]
  p.out_att    = out + (size_t)TTT * BBB * NINP;               // [T,B,S]
  p.out_gen    = out + (size_t)TTT * BBB * NINP + (size_t)TTT * BBB * SSS;  // [T,B]
  p.sync = (unsigned*)d_ws;
  p.wsf  = (float*)((char*)d_ws + 8192);

  hipMemsetAsync(d_ws, 0, 8192, stream);  // zero barrier counters/flags each call
  decoder_kernel<<<dim3(GDIM), dim3(NTHR), 0, stream>>>(p);
}

// Round 2
// 103491.003 us; speedup vs baseline: 6.2416x; 6.2416x over previous
//
#include <hip/hip_runtime.h>

#define NINP 34
#define NCC  128
#define NHH  512
#define BBB  64
#define SSS  2048
#define TTT  400
#define GEPS 1e-10f

#define GDIM 544
#define NTHR 256
#define NCHK 8        // attention S-chunks
#define SCHK 256      // S per chunk

#define JAX_PARTITIONABLE 1

// ws float offsets (after 8192-byte sync header)
#define OFF_H   0          // h double buffer: 2*3*B*NH = 196608
#define OFF_C   196608     // c: 3*B*NH = 98304
#define OFF_CTX 294912     // B*NC = 8192
#define OFF_Q   303104     // B*NC = 8192
#define OFF_E   311296     // B*S = 131072
#define OFF_P   442368     // B*NCHK*130 = 66560

// sync word layout (2048 uints): [0]=root, [1]=generation, [2]=qdone,
// [64+8*b]=per-b chunk flags, [1024+32*leaf]=leaf counters. All monotonic.
#define SY_ROOT 0
#define SY_GEN  1
#define SY_Q    2
#define SY_B(b)   (64 + 8 * (b))
#define SY_LEAF(l) (1024 + 32 * (l))

struct Params {
  const float* keys; const float* values;
  const int* lens;  const int* toks;
  const float* emb; const float* wq; const float* bq;
  const float* wc;  const float* bc; const float* bout;
  const float* wih[3]; const float* whh[3];
  const float* bih[3]; const float* bhh[3];
  const float* h0[3];  const float* c0[3];
  float* out_logits; float* out_att; float* out_gen;
  float* wsf; unsigned* sync;
};

__device__ __forceinline__ float4 ld4(const float* p) { return *(const float4*)p; }
__device__ __forceinline__ float sigf(float x) { return 1.0f / (1.0f + expf(-x)); }

// ---- relaxed agent-scope ops: plain sc1 accesses to the L3 coherence point.
// NO acquire/release: those emit buffer_inv / buffer_wbl2 (full L2 flush) on
// gfx940+, which was the 646 ms pathology. Ordering is done manually with
// s_waitcnt vmcnt(0) on the producer side + compiler barriers.
__device__ __forceinline__ unsigned aload(const unsigned* p) {
  return __hip_atomic_load(p, __ATOMIC_RELAXED, __HIP_MEMORY_SCOPE_AGENT);
}
__device__ __forceinline__ unsigned aadd(unsigned* p, unsigned v) {
  return __hip_atomic_fetch_add(p, v, __ATOMIC_RELAXED, __HIP_MEMORY_SCOPE_AGENT);
}
__device__ __forceinline__ void astore(unsigned* p, unsigned v) {
  __hip_atomic_store(p, v, __ATOMIC_RELAXED, __HIP_MEMORY_SCOPE_AGENT);
}
__device__ __forceinline__ float ldc(const float* p) {
  unsigned u = __hip_atomic_load((const unsigned*)p, __ATOMIC_RELAXED, __HIP_MEMORY_SCOPE_AGENT);
  return __uint_as_float(u);
}
__device__ __forceinline__ void stc(float* p, float v) {
  __hip_atomic_store((unsigned*)p, __float_as_uint(v), __ATOMIC_RELAXED, __HIP_MEMORY_SCOPE_AGENT);
}
__device__ __forceinline__ float4 ld4c(const float* p) {
  unsigned long long a = __hip_atomic_load((const unsigned long long*)p,
                                           __ATOMIC_RELAXED, __HIP_MEMORY_SCOPE_AGENT);
  unsigned long long b = __hip_atomic_load(((const unsigned long long*)p) + 1,
                                           __ATOMIC_RELAXED, __HIP_MEMORY_SCOPE_AGENT);
  float4 r;
  r.x = __uint_as_float((unsigned)a); r.y = __uint_as_float((unsigned)(a >> 32));
  r.z = __uint_as_float((unsigned)b); r.w = __uint_as_float((unsigned)(b >> 32));
  return r;
}
__device__ __forceinline__ void wait_vm0() {
  asm volatile("s_waitcnt vmcnt(0)" ::: "memory");
}
__device__ __forceinline__ void cbar() { asm volatile("" ::: "memory"); }

// Grid barrier, monotonic counters (no resets -> no store/atomic ordering
// hazard). 32 leaves x 17 blocks.
__device__ void gbar(unsigned* sync, unsigned& epoch) {
  wait_vm0();          // drain this wave's sc1 data stores to L3
  __syncthreads();     // all waves of the block drained
  if (threadIdx.x == 0) {
    epoch++;
    const int leaf = blockIdx.x / 17;
    if (aadd(&sync[SY_LEAF(leaf)], 1u) == 17u * epoch - 1u) {
      if (aadd(&sync[SY_ROOT], 1u) == 32u * epoch - 1u) {
        astore(&sync[SY_GEN], epoch);
      }
    }
    while (aload(&sync[SY_GEN]) < epoch) __builtin_amdgcn_s_sleep(2);
  }
  __syncthreads();
  cbar();
}

__device__ __forceinline__ void waitflag(unsigned* p, unsigned target) {
  if (threadIdx.x == 0) {
    while (aload(p) < target) __builtin_amdgcn_s_sleep(2);
  }
  __syncthreads();
  cbar();
}
__device__ __forceinline__ void postflag(unsigned* p) {
  wait_vm0();
  __syncthreads();
  if (threadIdx.x == 0) aadd(p, 1u);
}

// ---------------- Threefry2x32-20, jax.random.key(1) ----------------
__device__ __forceinline__ void tfr(unsigned& x0, unsigned& x1, int r) {
  x0 += x1; x1 = (x1 << r) | (x1 >> (32 - r)); x1 ^= x0;
}
__device__ unsigned threefry_bits(unsigned idx) {
  const unsigned k0 = 0u, k1 = 1u;
  const unsigned k2 = 0x1BD11BDAu ^ k0 ^ k1;
#if JAX_PARTITIONABLE
  unsigned x0 = 0u, x1 = idx;
#else
  const unsigned half = (TTT * BBB * NINP) / 2;
  const bool lo = idx < half;
  unsigned x0 = lo ? idx : idx - half;
  unsigned x1 = lo ? idx + half : idx;
#endif
  x0 += k0; x1 += k1;
  tfr(x0,x1,13); tfr(x0,x1,15); tfr(x0,x1,26); tfr(x0,x1,6);
  x0 += k1; x1 += k2 + 1u;
  tfr(x0,x1,17); tfr(x0,x1,29); tfr(x0,x1,16); tfr(x0,x1,24);
  x0 += k2; x1 += k0 + 2u;
  tfr(x0,x1,13); tfr(x0,x1,15); tfr(x0,x1,26); tfr(x0,x1,6);
  x0 += k0; x1 += k1 + 3u;
  tfr(x0,x1,17); tfr(x0,x1,29); tfr(x0,x1,16); tfr(x0,x1,24);
  x0 += k1; x1 += k2 + 4u;
  tfr(x0,x1,13); tfr(x0,x1,15); tfr(x0,x1,26); tfr(x0,x1,6);
  x0 += k2; x1 += k0 + 5u;
#if JAX_PARTITIONABLE
  return x0 ^ x1;
#else
  return lo ? x0 : x1;
#endif
}
__device__ __forceinline__ float gumbel(unsigned idx) {
  unsigned bits = threefry_bits(idx);
  float u = __uint_as_float((bits >> 9) | 0x3f800000u) - 1.0f;
  u = fmaxf(u, 0.0f);
  return -logf(GEPS - logf(u + GEPS));
}

// ---------------- LSTM layer phase ----------------
template<int L>
__device__ void lstm_layer(const Params& p, int t, const float* hin, float* hout,
                           float* sh, int bid, int tid) {
  const float* hin_l = hin + L * BBB * NHH;
  float* houtl = hout + L * BBB * NHH;
  float* cl = p.wsf + OFF_C + L * BBB * NHH;
  const float* xlow = (L == 0) ? (const float*)0 : (hout + (L - 1) * BBB * NHH);

  const int b = tid & 63;
  const int g = tid >> 6;
  const int j = bid;
  const int row = g * NHH + j;
  const int insz = (L == 0) ? (2 * NCC) : NHH;
  const int nx = insz >> 7;

  const float* wr  = p.wih[L] + (size_t)row * insz;
  const float* wr2 = p.whh[L] + (size_t)row * NHH;
  float acc = p.bih[L][row] + p.bhh[L][row];
  float s0 = 0.f, s1 = 0.f, s2 = 0.f, s3 = 0.f;

  for (int cc = 0; cc < nx + 4; ++cc) {
    const bool isx = cc < nx;
    const int off = (isx ? cc : cc - nx) << 7;
    __syncthreads();
    for (int i = tid; i < 2048; i += NTHR) {
      const int rb = i >> 5;
      const int kk = (i & 31) << 2;
      float4 v;
      if (L == 0) {
        if (isx) {
          if (cc == 0) v = ld4(p.emb + (size_t)p.toks[rb * TTT + t] * NCC + kk); // read-only
          else         v = ld4c(p.wsf + OFF_CTX + rb * NCC + kk);                // kernel-written
        } else {
          v = ld4c(hin_l + (size_t)rb * NHH + off + kk);
        }
      } else {
        if (isx) v = ld4c(xlow + (size_t)rb * NHH + off + kk);
        else     v = ld4c(hin_l + (size_t)rb * NHH + off + kk);
      }
      *(float4*)&sh[rb * 132 + kk] = v;
    }
    __syncthreads();
    const float* wp = (isx ? wr : wr2) + off;
    const float* xr = sh + b * 132;
#pragma unroll 8
    for (int k = 0; k < 128; k += 4) {
      float4 w = ld4(wp + k);
      float4 x = ld4(xr + k);
      s0 = fmaf(w.x, x.x, s0); s1 = fmaf(w.y, x.y, s1);
      s2 = fmaf(w.z, x.z, s2); s3 = fmaf(w.w, x.w, s3);
    }
  }
  acc += (s0 + s1) + (s2 + s3);

  float* gl = sh + 8448;
  gl[g * 64 + b] = acc;
  __syncthreads();
  if (tid < 64) {
    const int bb = tid;
    const float iv = gl[bb], fv = gl[64 + bb], gv = gl[128 + bb], ov = gl[192 + bb];
    const float cold = cl[bb * NHH + j];                 // block-private: plain
    const float cnew = sigf(fv) * cold + sigf(iv) * tanhf(gv);
    const float hnew = sigf(ov) * tanhf(cnew);
    cl[bb * NHH + j] = cnew;                             // block-private: plain
    stc(&houtl[bb * NHH + j], hnew);                     // cross-block: coherent
  }
}

// ---------------- fused attention phase ----------------
__device__ void attend_phase(const Params& p, int a, int t, const float* h3,
                             float* sh, int bid, int tid, bool wout) {
  float* wsf = p.wsf;
  unsigned* sync = p.sync;

  if (bid >= NHH) {
    const int cb = bid - NHH;  // 0..31
    {
      const int b = tid & 63;
      const int ci = tid >> 6;
      const int c = cb * 4 + ci;
      const float* wr = p.wq + (size_t)c * NHH;
      float s0 = 0.f, s1 = 0.f, s2 = 0.f, s3 = 0.f;
      for (int cc = 0; cc < 4; ++cc) {
        __syncthreads();
        for (int i = tid; i < 2048; i += NTHR) {
          const int rb = i >> 5;
          const int kk = (i & 31) << 2;
          *(float4*)&sh[rb * 132 + kk] = ld4c(h3 + (size_t)rb * NHH + cc * 128 + kk);
        }
        __syncthreads();
        const float* wp = wr + cc * 128;
        const float* xr = sh + b * 132;
#pragma unroll 8
        for (int k = 0; k < 128; k += 4) {
          float4 w = ld4(wp + k);
          float4 x = ld4(xr + k);
          s0 = fmaf(w.x, x.x, s0); s1 = fmaf(w.y, x.y, s1);
          s2 = fmaf(w.z, x.z, s2); s3 = fmaf(w.w, x.w, s3);
        }
      }
      stc(&wsf[OFF_Q + b * NCC + c], p.bq[c] + (s0 + s1) + (s2 + s3));
    }
    postflag(&sync[SY_Q]);

    for (int bi = 0; bi < 2; ++bi) {
      const int b = cb * 2 + bi;
      waitflag(&sync[SY_B(b)], (unsigned)(NCHK * (a + 1)));
      const float* pb = wsf + OFF_P + ((size_t)b * NCHK) * 130;
      float m = -1e30f;
#pragma unroll
      for (int ch = 0; ch < NCHK; ++ch) m = fmaxf(m, ldc(&pb[ch * 130]));
      float Lsum = 0.f;
#pragma unroll
      for (int ch = 0; ch < NCHK; ++ch)
        Lsum += ldc(&pb[ch * 130 + 1]) * expf(ldc(&pb[ch * 130]) - m);

      float* us = sh;  // 640: [h3 row | ctx]
      if (tid < NCC) {
        float v = 0.f;
#pragma unroll
        for (int ch = 0; ch < NCHK; ++ch)
          v += ldc(&pb[ch * 130 + 2 + tid]) * expf(ldc(&pb[ch * 130]) - m);
        v /= Lsum;
        stc(&wsf[OFF_CTX + b * NCC + tid], v);
        us[NHH + tid] = v;
      }
      for (int k = tid; k < NHH; k += NTHR) us[k] = ldc(&h3[(size_t)b * NHH + k]);
      __syncthreads();

      if (wout) {
        const float* eb = wsf + OFF_E + (size_t)b * SSS;
        float* ao = p.out_att + ((size_t)t * BBB + b) * SSS;
        for (int s = tid; s < SSS; s += NTHR) ao[s] = expf(ldc(&eb[s]) - m) / Lsum;
        float* zs = sh + 704;
        if (tid < NCC) {
          const float* wr = p.wc + (size_t)tid * (NHH + NCC);
          float s0 = 0.f, s1 = 0.f, s2 = 0.f, s3 = 0.f;
#pragma unroll 8
          for (int k = 0; k < NHH + NCC; k += 4) {
            float4 w = ld4(wr + k);
            s0 = fmaf(w.x, us[k],     s0); s1 = fmaf(w.y, us[k + 1], s1);
            s2 = fmaf(w.z, us[k + 2], s2); s3 = fmaf(w.w, us[k + 3], s3);
          }
          float z = (s0 + s1) + (s2 + s3) + p.bc[tid];
          zs[tid] = (z >= 0.f) ? z : 0.01f * z;
        }
        __syncthreads();
        float* lg = sh + 840;
        if (tid < NINP) {
          const float* er = p.emb + tid * NCC;
          float s0 = 0.f, s1 = 0.f, s2 = 0.f, s3 = 0.f;
#pragma unroll 8
          for (int k = 0; k < NCC; k += 4) {
            float4 w = ld4(er + k);
            s0 = fmaf(w.x, zs[k],     s0); s1 = fmaf(w.y, zs[k + 1], s1);
            s2 = fmaf(w.z, zs[k + 2], s2); s3 = fmaf(w.w, zs[k + 3], s3);
          }
          const float lgt = (s0 + s1) + (s2 + s3) + p.bout[tid];
          p.out_logits[((size_t)t * BBB + b) * NINP + tid] = lgt;
          lg[tid] = lgt + gumbel((unsigned)(t * (BBB * NINP) + b * NINP + tid));
        }
        __syncthreads();
        if (tid == 0) {
          float bv = lg[0]; int bix = 0;
          for (int i = 1; i < NINP; ++i) if (lg[i] > bv) { bv = lg[i]; bix = i; }
          p.out_gen[t * BBB + b] = (float)bix;
        }
        __syncthreads();
      } else {
        __syncthreads();
      }
    }
  } else {
    const int b = bid >> 3;
    const int ch = bid & 7;
    const int sbase = ch * SCHK;
    waitflag(&sync[SY_Q], (unsigned)(32 * (a + 1)));

    float* qs = sh;
    float* ps = sh + 128;
    float* red = sh + 384;
    if (tid < NCC) qs[tid] = ldc(&wsf[OFF_Q + b * NCC + tid]);
    const int lenb = p.lens[b];
    __syncthreads();

    const int s = sbase + tid;
    const float* kr = p.keys + ((size_t)b * SSS + s) * NCC;
    float e0 = 0.f, e1 = 0.f, e2 = 0.f, e3 = 0.f;
#pragma unroll 8
    for (int c = 0; c < NCC; c += 4) {
      float4 kv = ld4(kr + c);
      e0 = fmaf(qs[c],     kv.x, e0); e1 = fmaf(qs[c + 1], kv.y, e1);
      e2 = fmaf(qs[c + 2], kv.z, e2); e3 = fmaf(qs[c + 3], kv.w, e3);
    }
    float e = (e0 + e1) + (e2 + e3);
    const bool msk = s < lenb;
    e = msk ? e : -1e6f;
    stc(&wsf[OFF_E + (size_t)b * SSS + s], e);

    float mx = e;
#pragma unroll
    for (int off = 32; off; off >>= 1) mx = fmaxf(mx, __shfl_xor(mx, off));
    if ((tid & 63) == 0) red[tid >> 6] = mx;
    __syncthreads();
    const float mc = fmaxf(fmaxf(red[0], red[1]), fmaxf(red[2], red[3]));
    const float pv = msk ? expf(e - mc) : 0.f;
    ps[tid] = pv;
    float ls = pv;
#pragma unroll
    for (int off = 32; off; off >>= 1) ls += __shfl_xor(ls, off);
    if ((tid & 63) == 0) red[4 + (tid >> 6)] = ls;
    __syncthreads();
    const float lc = (red[4] + red[5]) + (red[6] + red[7]);

    const int c4 = (tid & 31) << 2;
    const int sg = tid >> 5;
    float r0 = 0.f, r1 = 0.f, r2 = 0.f, r3 = 0.f;
    const float* vb = p.values + ((size_t)b * SSS + sbase + sg * 32) * NCC + c4;
#pragma unroll 4
    for (int i2 = 0; i2 < 32; ++i2) {
      const float pw = ps[sg * 32 + i2];
      float4 vv = ld4(vb + (size_t)i2 * NCC);
      r0 = fmaf(pw, vv.x, r0); r1 = fmaf(pw, vv.y, r1);
      r2 = fmaf(pw, vv.z, r2); r3 = fmaf(pw, vv.w, r3);
    }
    __syncthreads();
    *(float4*)&red[sg * 132 + c4] = make_float4(r0, r1, r2, r3);
    __syncthreads();
    float* pout = wsf + OFF_P + ((size_t)b * NCHK + ch) * 130;
    if (tid < NCC) {
      float sum = 0.f;
#pragma unroll
      for (int sg2 = 0; sg2 < 8; ++sg2) sum += red[sg2 * 132 + tid];
      stc(&pout[2 + tid], sum);
    }
    if (tid == 0) { stc(&pout[0], mc); stc(&pout[1], lc); }
    postflag(&sync[SY_B(b)]);
  }
}

extern "C" __global__ void __launch_bounds__(NTHR, 4)
decoder_kernel(Params p) {
  __shared__ float sh[8704];  // 34,816 B
  const int bid = blockIdx.x;
  const int tid = threadIdx.x;
  unsigned epoch = 0;
  unsigned* sync = p.sync;
  float* wsf = p.wsf;

  // init: LSTM block j owns hidden index j — init its own h (coherent, read by
  // all) and c (plain, block-private forever after)
  if (bid < NHH && tid < 192) {
    const int l = tid >> 6, b = tid & 63;
    stc(&wsf[OFF_H + ((size_t)l * BBB + b) * NHH + bid], p.h0[l][bid]);
    wsf[OFF_C + ((size_t)l * BBB + b) * NHH + bid] = p.c0[l][bid];
  }
  gbar(sync, epoch);

  attend_phase(p, 0, -1, wsf + OFF_H + 2 * BBB * NHH, sh, bid, tid, false);
  gbar(sync, epoch);

  for (int t = 0; t < TTT; ++t) {
    const float* hin = wsf + OFF_H + ((t & 1) ? 3 * BBB * NHH : 0);
    float* hout      = wsf + OFF_H + ((t & 1) ? 0 : 3 * BBB * NHH);

    if (bid < NHH) lstm_layer<0>(p, t, hin, hout, sh, bid, tid);
    gbar(sync, epoch);
    if (bid < NHH) lstm_layer<1>(p, t, hin, hout, sh, bid, tid);
    gbar(sync, epoch);
    if (bid < NHH) lstm_layer<2>(p, t, hin, hout, sh, bid, tid);
    gbar(sync, epoch);
    attend_phase(p, t + 1, t, hout + 2 * BBB * NHH, sh, bid, tid, true);
    gbar(sync, epoch);
  }
}

extern "C" void kernel_launch(void* const* d_in, const int* in_sizes, int n_in,
                              void* d_out, int out_size, void* d_ws, size_t ws_size,
                              hipStream_t stream) {
  Params p;
  p.keys   = (const float*)d_in[0];
  p.values = (const float*)d_in[1];
  p.lens   = (const int*)d_in[2];
  p.toks   = (const int*)d_in[3];
  p.emb    = (const float*)d_in[4];
  p.wq     = (const float*)d_in[5];
  p.bq     = (const float*)d_in[6];
  p.wc     = (const float*)d_in[7];
  p.bc     = (const float*)d_in[8];
  p.bout   = (const float*)d_in[9];
  for (int l = 0; l < 3; ++l) {
    p.wih[l] = (const float*)d_in[10 + 6 * l];
    p.whh[l] = (const float*)d_in[11 + 6 * l];
    p.bih[l] = (const float*)d_in[12 + 6 * l];
    p.bhh[l] = (const float*)d_in[13 + 6 * l];
    p.h0[l]  = (const float*)d_in[14 + 6 * l];
    p.c0[l]  = (const float*)d_in[15 + 6 * l];
  }
  float* out = (float*)d_out;
  p.out_logits = out;
  p.out_att    = out + (size_t)TTT * BBB * NINP;
  p.out_gen    = out + (size_t)TTT * BBB * NINP + (size_t)TTT * BBB * SSS;
  p.sync = (unsigned*)d_ws;
  p.wsf  = (float*)((char*)d_ws + 8192);

  hipMemsetAsync(d_ws, 0, 8192, stream);
  decoder_kernel<<<dim3(GDIM), dim3(NTHR), 0, stream>>>(p);
}